// Round 1
// baseline (637.168 us; speedup 1.0000x reference)
//
#include <hip/hip_runtime.h>
#include <hip/hip_bf16.h>

#define HID 2048
#define SEQN 2048
#define NH 32
#define HD 64
#define NB 2
#define MROWS (NB * SEQN)  // 4096

using short8 = __attribute__((ext_vector_type(8))) short;
using f32x4  = __attribute__((ext_vector_type(4))) float;

__device__ __forceinline__ unsigned short f2bf(float f) {
  unsigned u = __float_as_uint(f);
  u += 0x7FFFu + ((u >> 16) & 1u);   // RNE
  return (unsigned short)(u >> 16);
}

__device__ __forceinline__ void gload16(const void* g, void* l) {
  __builtin_amdgcn_global_load_lds(
      (const __attribute__((address_space(1))) void*)g,
      (__attribute__((address_space(3))) void*)l, 16, 0, 0);
}

// ---------------- converters ----------------
__global__ void cvt_x_k(const float* __restrict__ x, unsigned short* __restrict__ o, int n4) {
  int i = blockIdx.x * blockDim.x + threadIdx.x;
  int stride = gridDim.x * blockDim.x;
  for (; i < n4; i += stride) {
    float4 v = ((const float4*)x)[i];
    ushort4 r;
    r.x = f2bf(v.x); r.y = f2bf(v.y); r.z = f2bf(v.z); r.w = f2bf(v.w);
    ((ushort4*)o)[i] = r;
  }
}

// Wt[n][k] = W[k][n], fp32 -> bf16
__global__ void cvt_w_k(const float* W0, const float* W1, const float* W2, const float* W3,
                        unsigned short* o0, unsigned short* o1, unsigned short* o2, unsigned short* o3) {
  const float* W = blockIdx.z == 0 ? W0 : blockIdx.z == 1 ? W1 : blockIdx.z == 2 ? W2 : W3;
  unsigned short* o = blockIdx.z == 0 ? o0 : blockIdx.z == 1 ? o1 : blockIdx.z == 2 ? o2 : o3;
  __shared__ float t[32][33];
  int n0 = blockIdx.x * 32, k0 = blockIdx.y * 32;
  int x = threadIdx.x, y = threadIdx.y;
#pragma unroll
  for (int i = 0; i < 4; i++)
    t[y + 8 * i][x] = W[(size_t)(k0 + y + 8 * i) * HID + n0 + x];
  __syncthreads();
#pragma unroll
  for (int i = 0; i < 4; i++)
    o[(size_t)(n0 + y + 8 * i) * HID + k0 + x] = f2bf(t[x][y + 8 * i]);
}

// ---------------- GEMM: C[m,n] = sum_k A[m,k]*Bt[n,k] + bias[n] ----------------
// mode 0: bf16 out, head-major [B,H,S,64]   (Q, K)
// mode 1: bf16 out, transposed [B,H,64,S]   (V^T)
// mode 2: f32 out, row-major [M, HID]       (final)
__global__ __launch_bounds__(256) void gemm_k(const unsigned short* __restrict__ A,
                                              const unsigned short* __restrict__ Bt,
                                              const float* __restrict__ bias,
                                              void* __restrict__ out, int mode) {
  __shared__ __align__(16) unsigned short As[128 * 64];
  __shared__ __align__(16) unsigned short Bs[128 * 64];
  const int tid = threadIdx.x;
  const int wid = tid >> 6, lane = tid & 63;
  const int l15 = lane & 15, lhi = lane >> 4;
  const int wr = wid >> 1, wc = wid & 1;
  const int tileM = blockIdx.y * 128, tileN = blockIdx.x * 128;
  f32x4 acc[4][4] = {};

  for (int k0 = 0; k0 < HID; k0 += 64) {
#pragma unroll
    for (int i = 0; i < 4; i++) {
      int X = (i * 256 + tid) * 16;       // linear LDS byte
      int r = X >> 7, y = X & 127;        // row (128B rows), offset in row
      int srcb = y ^ ((r & 7) << 4);      // pre-swizzled global source (m173 pattern)
      const char* ga = (const char*)A + ((size_t)(tileM + r) * HID + k0) * 2 + srcb;
      const char* gb = (const char*)Bt + ((size_t)(tileN + r) * HID + k0) * 2 + srcb;
      gload16(ga, (char*)As + i * 4096 + wid * 1024);
      gload16(gb, (char*)Bs + i * 4096 + wid * 1024);
    }
    __syncthreads();
#pragma unroll
    for (int ks = 0; ks < 2; ks++) {
      short8 af[4], bfr[4];
      int off = ks * 64 + lhi * 16;
#pragma unroll
      for (int mf = 0; mf < 4; mf++) {
        int r = wr * 64 + mf * 16 + l15;
        af[mf] = *(const short8*)((const char*)As + r * 128 + (off ^ ((r & 7) << 4)));
      }
#pragma unroll
      for (int nf = 0; nf < 4; nf++) {
        int r = wc * 64 + nf * 16 + l15;
        bfr[nf] = *(const short8*)((const char*)Bs + r * 128 + (off ^ ((r & 7) << 4)));
      }
#pragma unroll
      for (int mf = 0; mf < 4; mf++)
#pragma unroll
        for (int nf = 0; nf < 4; nf++)
          acc[mf][nf] = __builtin_amdgcn_mfma_f32_16x16x32_bf16(af[mf], bfr[nf], acc[mf][nf], 0, 0, 0);
    }
    __syncthreads();
  }

#pragma unroll
  for (int mf = 0; mf < 4; mf++) {
#pragma unroll
    for (int nf = 0; nf < 4; nf++) {
      int n = tileN + wc * 64 + nf * 16 + l15;
      float bv = bias[n];
#pragma unroll
      for (int reg = 0; reg < 4; reg++) {
        int m = tileM + wr * 64 + mf * 16 + lhi * 4 + reg;
        float v = acc[mf][nf][reg] + bv;
        if (mode == 0) {
          int b = m >> 11, s = m & 2047, h = n >> 6, dd = n & 63;
          ((unsigned short*)out)[((((size_t)b * NH + h) * SEQN + s) << 6) + dd] = f2bf(v);
        } else if (mode == 1) {
          int b = m >> 11, s = m & 2047, h = n >> 6, dd = n & 63;
          ((unsigned short*)out)[((((size_t)b * NH + h) << 6) + dd) * SEQN + s] = f2bf(v);
        } else {
          ((float*)out)[(size_t)m * HID + n] = v;
        }
      }
    }
  }
}

// ---------------- flash attention ----------------
// Q,K: [B,H,S,64] bf16 ; Vt: [B,H,64,S] bf16 ; ctx out: [B,S,H*64] bf16
__global__ __launch_bounds__(256) void attn_k(const unsigned short* __restrict__ Q,
                                              const unsigned short* __restrict__ K,
                                              const unsigned short* __restrict__ Vt,
                                              unsigned short* __restrict__ ctx) {
  __shared__ __align__(16) unsigned short Qs[32 * 64];    // 4KB, 128B rows, swz
  __shared__ __align__(16) unsigned short Ks[128 * 64];   // 16KB
  __shared__ __align__(16) unsigned short Vs[64 * 128];   // 16KB, 256B rows, swz
  __shared__ __align__(16) float Ss[32 * 129];            // padded f32 scores
  __shared__ __align__(16) unsigned short Ps[32 * 128];   // bf16 P, 256B rows, swz
  __shared__ float m_s[32], l_s[32], c_s[32];
  const int tid = threadIdx.x;
  const int wid = tid >> 6, lane = tid & 63;
  const int l15 = lane & 15, lhi = lane >> 4;
  const int bh = blockIdx.y;
  const int q0 = blockIdx.x * 32;
  const unsigned short* Qh = Q + (size_t)bh * SEQN * HD;
  const unsigned short* Kh = K + (size_t)bh * SEQN * HD;
  const unsigned short* Vh = Vt + (size_t)bh * HD * SEQN;

  {  // stage Q tile once (32 rows x 128B)
    int X = tid * 16;
    int r = X >> 7, y = X & 127;
    const char* g = (const char*)Qh + ((size_t)(q0 + r) * HD) * 2 + (y ^ ((r & 7) << 4));
    gload16(g, (char*)Qs + wid * 1024);
  }
  if (tid < 32) { m_s[tid] = -1e30f; l_s[tid] = 0.f; }
  f32x4 oacc[2] = {};

  for (int kt = 0; kt < SEQN; kt += 128) {
#pragma unroll
    for (int i = 0; i < 4; i++) {
      int X = (i * 256 + tid) * 16;
      {  // K tile: 128 rows x 128B
        int r = X >> 7, y = X & 127;
        const char* g = (const char*)Kh + ((size_t)(kt + r) * HD) * 2 + (y ^ ((r & 7) << 4));
        gload16(g, (char*)Ks + i * 4096 + wid * 1024);
      }
      {  // V tile: 64 rows (dd) x 256B (128 kv)
        int r = X >> 8, y = X & 255;
        const char* g = (const char*)Vh + ((size_t)r * SEQN + kt) * 2 + (y ^ ((r & 7) << 4));
        gload16(g, (char*)Vs + i * 4096 + wid * 1024);
      }
    }
    __syncthreads();

    // S = (Q K^T) * scale ; wave wid owns kv cols [wid*32, wid*32+32)
    f32x4 sacc[2][2] = {};
#pragma unroll
    for (int ks = 0; ks < 2; ks++) {
      short8 qa[2], ka[2];
      int off = ks * 64 + lhi * 16;
#pragma unroll
      for (int qi = 0; qi < 2; qi++) {
        int r = qi * 16 + l15;
        qa[qi] = *(const short8*)((const char*)Qs + r * 128 + (off ^ ((r & 7) << 4)));
      }
#pragma unroll
      for (int nf = 0; nf < 2; nf++) {
        int r = wid * 32 + nf * 16 + l15;
        ka[nf] = *(const short8*)((const char*)Ks + r * 128 + (off ^ ((r & 7) << 4)));
      }
#pragma unroll
      for (int qi = 0; qi < 2; qi++)
#pragma unroll
        for (int nf = 0; nf < 2; nf++)
          sacc[qi][nf] = __builtin_amdgcn_mfma_f32_16x16x32_bf16(qa[qi], ka[nf], sacc[qi][nf], 0, 0, 0);
    }
#pragma unroll
    for (int qi = 0; qi < 2; qi++)
#pragma unroll
      for (int nf = 0; nf < 2; nf++)
#pragma unroll
        for (int reg = 0; reg < 4; reg++) {
          int row = qi * 16 + lhi * 4 + reg;
          int col = wid * 32 + nf * 16 + l15;
          Ss[row * 129 + col] = sacc[qi][nf][reg] * 0.125f;
        }
    __syncthreads();

    // online softmax: 8 threads per q-row, 16 cols each
    {
      int srow = tid >> 3, g = tid & 7, c0 = g * 16;
      float mold = m_s[srow], lold = l_s[srow];
      float sv[16];
      float tmax = -1e30f;
#pragma unroll
      for (int j = 0; j < 16; j++) { sv[j] = Ss[srow * 129 + c0 + j]; tmax = fmaxf(tmax, sv[j]); }
      tmax = fmaxf(tmax, __shfl_xor(tmax, 1));
      tmax = fmaxf(tmax, __shfl_xor(tmax, 2));
      tmax = fmaxf(tmax, __shfl_xor(tmax, 4));
      float mnew = fmaxf(mold, tmax);
      float corr = __expf(mold - mnew);
      float rsum = 0.f;
      short8 p0, p1;
#pragma unroll
      for (int j = 0; j < 8; j++) { float p = __expf(sv[j] - mnew); rsum += p; p0[j] = (short)f2bf(p); }
#pragma unroll
      for (int j = 0; j < 8; j++) { float p = __expf(sv[8 + j] - mnew); rsum += p; p1[j] = (short)f2bf(p); }
      rsum += __shfl_xor(rsum, 1);
      rsum += __shfl_xor(rsum, 2);
      rsum += __shfl_xor(rsum, 4);
      if (g == 0) { m_s[srow] = mnew; l_s[srow] = lold * corr + rsum; c_s[srow] = corr; }
      *(short8*)((char*)Ps + srow * 256 + ((c0 * 2) ^ ((srow & 7) << 4))) = p0;
      *(short8*)((char*)Ps + srow * 256 + ((c0 * 2 + 16) ^ ((srow & 7) << 4))) = p1;
    }
    __syncthreads();

    // rescale O, then O += P @ V ; wave wid owns dd cols [wid*16, wid*16+16)
#pragma unroll
    for (int qi = 0; qi < 2; qi++)
#pragma unroll
      for (int reg = 0; reg < 4; reg++) {
        int row = qi * 16 + lhi * 4 + reg;
        oacc[qi][reg] *= c_s[row];
      }
#pragma unroll
    for (int ks = 0; ks < 4; ks++) {
      int off = ks * 64 + lhi * 16;
      short8 pa[2], vb;
#pragma unroll
      for (int qi = 0; qi < 2; qi++) {
        int r = qi * 16 + l15;
        pa[qi] = *(const short8*)((const char*)Ps + r * 256 + (off ^ ((r & 7) << 4)));
      }
      {
        int r = wid * 16 + l15;
        vb = *(const short8*)((const char*)Vs + r * 256 + (off ^ ((r & 7) << 4)));
      }
#pragma unroll
      for (int qi = 0; qi < 2; qi++)
        oacc[qi] = __builtin_amdgcn_mfma_f32_16x16x32_bf16(pa[qi], vb, oacc[qi], 0, 0, 0);
    }
    __syncthreads();
  }

  const int b = bh >> 5, h = bh & 31;
#pragma unroll
  for (int qi = 0; qi < 2; qi++)
#pragma unroll
    for (int reg = 0; reg < 4; reg++) {
      int row = qi * 16 + lhi * 4 + reg;
      float inv = 1.f / l_s[row];
      size_t idx = ((size_t)(b * SEQN + q0 + row)) * HID + h * HD + wid * 16 + l15;
      ctx[idx] = f2bf(oacc[qi][reg] * inv);
    }
}

// ---------------- launch ----------------
extern "C" void kernel_launch(void* const* d_in, const int* in_sizes, int n_in,
                              void* d_out, int out_size, void* d_ws, size_t ws_size,
                              hipStream_t stream) {
  const float* X  = (const float*)d_in[0];
  const float* Wq = (const float*)d_in[1];
  const float* bq = (const float*)d_in[2];
  const float* Wk = (const float*)d_in[3];
  const float* bk = (const float*)d_in[4];
  const float* Wv = (const float*)d_in[5];
  const float* bv = (const float*)d_in[6];
  const float* Wo = (const float*)d_in[7];
  const float* bo = (const float*)d_in[8];
  float* out = (float*)d_out;
  char* ws = (char*)d_ws;

  unsigned short* Xb  = (unsigned short*)(ws);                  // 16MB  [4096,2048] bf16
  unsigned short* Wtq = (unsigned short*)(ws + (16u << 20));    // 8MB   [N,K] bf16
  unsigned short* Wtk = (unsigned short*)(ws + (24u << 20));
  unsigned short* Wtv = (unsigned short*)(ws + (32u << 20));
  unsigned short* Wto = (unsigned short*)(ws + (40u << 20));
  unsigned short* Qb  = (unsigned short*)(ws + (48u << 20));    // 16MB [B,H,S,64]
  unsigned short* Kb  = (unsigned short*)(ws + (64u << 20));    // 16MB [B,H,S,64]
  unsigned short* Vtb = (unsigned short*)(ws + (80u << 20));    // 16MB [B,H,64,S]
  unsigned short* Cb  = (unsigned short*)(ws + (96u << 20));    // 16MB [B,S,2048]

  cvt_x_k<<<dim3(1024), dim3(256), 0, stream>>>(X, Xb, (MROWS * HID) / 4);
  cvt_w_k<<<dim3(64, 64, 4), dim3(32, 8), 0, stream>>>(Wq, Wk, Wv, Wo, Wtq, Wtk, Wtv, Wto);
  gemm_k<<<dim3(16, 32), dim3(256), 0, stream>>>(Xb, Wtq, bq, (void*)Qb, 0);
  gemm_k<<<dim3(16, 32), dim3(256), 0, stream>>>(Xb, Wtk, bk, (void*)Kb, 0);
  gemm_k<<<dim3(16, 32), dim3(256), 0, stream>>>(Xb, Wtv, bv, (void*)Vtb, 1);
  attn_k<<<dim3(64, 64), dim3(256), 0, stream>>>(Qb, Kb, Vtb, Cb);
  gemm_k<<<dim3(16, 32), dim3(256), 0, stream>>>(Cb, Wto, bo, (void*)out, 2);
}

// Round 5
// 452.256 us; speedup vs baseline: 1.4089x; 1.4089x over previous
//
#include <hip/hip_runtime.h>
#include <hip/hip_bf16.h>

#define HID 2048
#define SEQN 2048
#define NH 32
#define HD 64
#define NB 2
#define MROWS (NB * SEQN)  // 4096

using short8 = __attribute__((ext_vector_type(8))) short;
using f32x4  = __attribute__((ext_vector_type(4))) float;
using u32x2  = __attribute__((ext_vector_type(2))) unsigned;

__device__ __forceinline__ unsigned short f2bf(float f) {
  unsigned u = __float_as_uint(f);
  u += 0x7FFFu + ((u >> 16) & 1u);   // RNE
  return (unsigned short)(u >> 16);
}

__device__ __forceinline__ void gload16(const void* g, void* l) {
  __builtin_amdgcn_global_load_lds(
      (const __attribute__((address_space(1))) void*)g,
      (__attribute__((address_space(3))) void*)l, 16, 0, 0);
}

// ---------------- converters ----------------
__global__ void cvt_x_k(const float* __restrict__ x, unsigned short* __restrict__ o, int n4) {
  int i = blockIdx.x * blockDim.x + threadIdx.x;
  int stride = gridDim.x * blockDim.x;
  for (; i < n4; i += stride) {
    float4 v = ((const float4*)x)[i];
    ushort4 r;
    r.x = f2bf(v.x); r.y = f2bf(v.y); r.z = f2bf(v.z); r.w = f2bf(v.w);
    ((ushort4*)o)[i] = r;
  }
}

// Wt[n][k] = W[k][n], fp32 -> bf16
__global__ void cvt_w_k(const float* W0, const float* W1, const float* W2, const float* W3,
                        unsigned short* o0, unsigned short* o1, unsigned short* o2, unsigned short* o3) {
  const float* W = blockIdx.z == 0 ? W0 : blockIdx.z == 1 ? W1 : blockIdx.z == 2 ? W2 : W3;
  unsigned short* o = blockIdx.z == 0 ? o0 : blockIdx.z == 1 ? o1 : blockIdx.z == 2 ? o2 : o3;
  __shared__ float t[32][33];
  int n0 = blockIdx.x * 32, k0 = blockIdx.y * 32;
  int x = threadIdx.x, y = threadIdx.y;
#pragma unroll
  for (int i = 0; i < 4; i++)
    t[y + 8 * i][x] = W[(size_t)(k0 + y + 8 * i) * HID + n0 + x];
  __syncthreads();
#pragma unroll
  for (int i = 0; i < 4; i++)
    o[(size_t)(n0 + y + 8 * i) * HID + k0 + x] = f2bf(t[x][y + 8 * i]);
}

// ---------------- QKV GEMM: frag-native epilogues ----------------
// z=0 -> Qf (scaled by 0.125 = 1/sqrt(64)), z=1 -> Kf, z=2 -> Vf
// Qf/Kf layout: [bh][s5][dg=dd>>3][r=s&31][j=dd&7]   (elem idx)
// Vf   layout: [bh][s5][kg=(s>>3)&3][d=dd][j=s&7]
__global__ __launch_bounds__(256) void qkv_gemm_k(const unsigned short* __restrict__ A,
                                                  const unsigned short* __restrict__ W0,
                                                  const unsigned short* __restrict__ W1,
                                                  const unsigned short* __restrict__ W2,
                                                  const float* __restrict__ b0,
                                                  const float* __restrict__ b1,
                                                  const float* __restrict__ b2,
                                                  unsigned short* __restrict__ o0,
                                                  unsigned short* __restrict__ o1,
                                                  unsigned short* __restrict__ o2) {
  const int z = blockIdx.z;
  const unsigned short* Bt = z == 0 ? W0 : z == 1 ? W1 : W2;
  const float* bias = z == 0 ? b0 : z == 1 ? b1 : b2;
  unsigned short* out = z == 0 ? o0 : z == 1 ? o1 : o2;
  const float scale = z == 0 ? 0.125f : 1.0f;

  __shared__ __align__(16) unsigned short As[128 * 64];
  __shared__ __align__(16) unsigned short Bs[128 * 64];
  const int tid = threadIdx.x;
  const int wid = tid >> 6, lane = tid & 63;
  const int l15 = lane & 15, lhi = lane >> 4;
  const int wr = wid >> 1, wc = wid & 1;
  const int tileM = blockIdx.y * 128, tileN = blockIdx.x * 128;
  f32x4 acc[4][4] = {};

  for (int k0 = 0; k0 < HID; k0 += 64) {
#pragma unroll
    for (int i = 0; i < 4; i++) {
      int X = (i * 256 + tid) * 16;
      int r = X >> 7, y = X & 127;
      int srcb = y ^ ((r & 7) << 4);
      const char* ga = (const char*)A + ((size_t)(tileM + r) * HID + k0) * 2 + srcb;
      const char* gb = (const char*)Bt + ((size_t)(tileN + r) * HID + k0) * 2 + srcb;
      gload16(ga, (char*)As + i * 4096 + wid * 1024);
      gload16(gb, (char*)Bs + i * 4096 + wid * 1024);
    }
    __syncthreads();
#pragma unroll
    for (int ks = 0; ks < 2; ks++) {
      short8 af[4], bfr[4];
      int off = ks * 64 + lhi * 16;
#pragma unroll
      for (int mf = 0; mf < 4; mf++) {
        int r = wr * 64 + mf * 16 + l15;
        af[mf] = *(const short8*)((const char*)As + r * 128 + (off ^ ((r & 7) << 4)));
      }
#pragma unroll
      for (int nf = 0; nf < 4; nf++) {
        int r = wc * 64 + nf * 16 + l15;
        bfr[nf] = *(const short8*)((const char*)Bs + r * 128 + (off ^ ((r & 7) << 4)));
      }
#pragma unroll
      for (int mf = 0; mf < 4; mf++)
#pragma unroll
        for (int nf = 0; nf < 4; nf++)
          acc[mf][nf] = __builtin_amdgcn_mfma_f32_16x16x32_bf16(af[mf], bfr[nf], acc[mf][nf], 0, 0, 0);
    }
    __syncthreads();
  }

#pragma unroll
  for (int mf = 0; mf < 4; mf++) {
#pragma unroll
    for (int nf = 0; nf < 4; nf++) {
      int n = tileN + wc * 64 + nf * 16 + l15;
      float bv = bias[n];
      int h = n >> 6, dd = n & 63;
#pragma unroll
      for (int reg = 0; reg < 4; reg++) {
        int m = tileM + wr * 64 + mf * 16 + lhi * 4 + reg;
        float v = (acc[mf][nf][reg] + bv) * scale;
        int b = m >> 11, s = m & 2047;
        size_t base = (size_t)((b << 5) + h) * 131072 + (size_t)(s >> 5) * 2048;
        size_t idx = (z < 2) ? base + (size_t)((dd >> 3) * 256 + (s & 31) * 8 + (dd & 7))
                             : base + (size_t)(((s >> 3) & 3) * 512 + dd * 8 + (s & 7));
        out[idx] = f2bf(v);
      }
    }
  }
}

// ---------------- GEMM (final projection): C = A @ Wt^T + bias, f32 out ----------------
__global__ __launch_bounds__(256) void gemm_k(const unsigned short* __restrict__ A,
                                              const unsigned short* __restrict__ Bt,
                                              const float* __restrict__ bias,
                                              float* __restrict__ out) {
  __shared__ __align__(16) unsigned short As[128 * 64];
  __shared__ __align__(16) unsigned short Bs[128 * 64];
  const int tid = threadIdx.x;
  const int wid = tid >> 6, lane = tid & 63;
  const int l15 = lane & 15, lhi = lane >> 4;
  const int wr = wid >> 1, wc = wid & 1;
  const int tileM = blockIdx.y * 128, tileN = blockIdx.x * 128;
  f32x4 acc[4][4] = {};

  for (int k0 = 0; k0 < HID; k0 += 64) {
#pragma unroll
    for (int i = 0; i < 4; i++) {
      int X = (i * 256 + tid) * 16;
      int r = X >> 7, y = X & 127;
      int srcb = y ^ ((r & 7) << 4);
      const char* ga = (const char*)A + ((size_t)(tileM + r) * HID + k0) * 2 + srcb;
      const char* gb = (const char*)Bt + ((size_t)(tileN + r) * HID + k0) * 2 + srcb;
      gload16(ga, (char*)As + i * 4096 + wid * 1024);
      gload16(gb, (char*)Bs + i * 4096 + wid * 1024);
    }
    __syncthreads();
#pragma unroll
    for (int ks = 0; ks < 2; ks++) {
      short8 af[4], bfr[4];
      int off = ks * 64 + lhi * 16;
#pragma unroll
      for (int mf = 0; mf < 4; mf++) {
        int r = wr * 64 + mf * 16 + l15;
        af[mf] = *(const short8*)((const char*)As + r * 128 + (off ^ ((r & 7) << 4)));
      }
#pragma unroll
      for (int nf = 0; nf < 4; nf++) {
        int r = wc * 64 + nf * 16 + l15;
        bfr[nf] = *(const short8*)((const char*)Bs + r * 128 + (off ^ ((r & 7) << 4)));
      }
#pragma unroll
      for (int mf = 0; mf < 4; mf++)
#pragma unroll
        for (int nf = 0; nf < 4; nf++)
          acc[mf][nf] = __builtin_amdgcn_mfma_f32_16x16x32_bf16(af[mf], bfr[nf], acc[mf][nf], 0, 0, 0);
    }
    __syncthreads();
  }

#pragma unroll
  for (int mf = 0; mf < 4; mf++) {
#pragma unroll
    for (int nf = 0; nf < 4; nf++) {
      int n = tileN + wc * 64 + nf * 16 + l15;
      float bv = bias[n];
#pragma unroll
      for (int reg = 0; reg < 4; reg++) {
        int m = tileM + wr * 64 + mf * 16 + lhi * 4 + reg;
        out[(size_t)m * HID + n] = acc[mf][nf][reg] + bv;
      }
    }
  }
}

// ---------------- flash attention: 16x16x32 MFMAs, round-1 numerics ----------------
// S^T tiles (a,b): kv=16a+lhi*4+reg, q=16b+l15 ; P via per-warp LDS.
// O^T tiles (d,b): dd=16d+lhi*4+reg, q=16b+l15 -> per-lane q -> scalar rescale.
// Qf/Kf: [bh][s5][dg][r][8] bf16 ; Vf: [bh][s5][kg][d][8] bf16 ; ctx: [B,S,2048] bf16
__global__ __launch_bounds__(256, 3) void attn_k(const unsigned short* __restrict__ Qf,
                                                 const unsigned short* __restrict__ Kf,
                                                 const unsigned short* __restrict__ Vf,
                                                 unsigned short* __restrict__ ctx) {
  __shared__ __align__(16) unsigned short Ks[2][4096];  // 8KB/buf: kv64 tile (2 s5 blocks)
  __shared__ __align__(16) unsigned short Vs[2][4096];
  __shared__ __align__(16) unsigned short Pb[4][1280];  // per-warp P: [q32][kv32], row stride 40sh = 80B (16B-aligned)
  const int tid = threadIdx.x;
  const int lane = tid & 63, wid = tid >> 6;
  const int l15 = lane & 15, lhi = lane >> 4;
  const int bh = blockIdx.y;
  const int s5q = blockIdx.x * 4 + wid;  // this warp's q 32-block
  const size_t hb = (size_t)bh * 131072;

  // Q B-frags (col=q=16b+l15, k=dd=32m+lhi*8+j), register-resident
  short8 qf[2][2];
#pragma unroll
  for (int m = 0; m < 2; m++)
#pragma unroll
    for (int b = 0; b < 2; b++)
      qf[m][b] = *(const short8*)(Qf + hb + (size_t)s5q * 2048 + (4 * m + lhi) * 256 + (16 * b + l15) * 8);

  f32x4 acc[4][2] = {};
  float mO[2] = {-1e30f, -1e30f}, lp[2] = {0.f, 0.f};

  const char* kg = (const char*)(Kf + hb);
  const char* vg = (const char*)(Vf + hb);
  char* Pw = (char*)&Pb[wid][0];

  // prologue: stage tile 0 into buf 0 (LDS dest wave-uniform; HW adds lane*16)
  gload16(kg + tid * 16, (char*)&Ks[0][0] + wid * 1024);
  gload16(kg + 4096 + tid * 16, (char*)&Ks[0][0] + 4096 + wid * 1024);
  gload16(vg + tid * 16, (char*)&Vs[0][0] + wid * 1024);
  gload16(vg + 4096 + tid * 16, (char*)&Vs[0][0] + 4096 + wid * 1024);

  for (int t = 0; t < 32; ++t) {
    __syncthreads();  // drains vmcnt/lgkmcnt; tile t staged, buf c^1 reads done
    const int c = t & 1;
    if (t + 1 < 32) {  // prefetch next tile into other buffer
      const char* kn = kg + (size_t)(t + 1) * 8192;
      const char* vn = vg + (size_t)(t + 1) * 8192;
      char* kl = (char*)&Ks[c ^ 1][0];
      char* vl = (char*)&Vs[c ^ 1][0];
      gload16(kn + tid * 16, kl + wid * 1024);
      gload16(kn + 4096 + tid * 16, kl + 4096 + wid * 1024);
      gload16(vn + tid * 16, vl + wid * 1024);
      gload16(vn + 4096 + tid * 16, vl + 4096 + wid * 1024);
    }
#pragma unroll
    for (int ks = 0; ks < 2; ++ks) {  // two kv32 sub-blocks
      const char* kb = (const char*)&Ks[c][0] + ks * 4096;
      const char* vb = (const char*)&Vs[c][0] + ks * 4096;
      // K A-frags: row=kv=16a+l15, k=dd=32m+lhi*8+j
      short8 kf[2][2];
#pragma unroll
      for (int a = 0; a < 2; a++)
#pragma unroll
        for (int m = 0; m < 2; m++)
          kf[a][m] = *(const short8*)(kb + (4 * m + lhi) * 512 + (16 * a + l15) * 16);
      // S^T tiles
      f32x4 sacc[2][2] = {};
#pragma unroll
      for (int a = 0; a < 2; a++)
#pragma unroll
        for (int b = 0; b < 2; b++)
#pragma unroll
          for (int m = 0; m < 2; m++)
            sacc[a][b] = __builtin_amdgcn_mfma_f32_16x16x32_bf16(kf[a][m], qf[m][b], sacc[a][b], 0, 0, 0);
      // per-b online softmax, classic always-rescale (round-1 numerics)
#pragma unroll
      for (int b = 0; b < 2; b++) {
        float tmax = sacc[0][b][0];
#pragma unroll
        for (int a = 0; a < 2; a++)
#pragma unroll
          for (int r = 0; r < 4; r++) tmax = fmaxf(tmax, sacc[a][b][r]);
        tmax = fmaxf(tmax, __shfl_xor(tmax, 16));
        tmax = fmaxf(tmax, __shfl_xor(tmax, 32));
        float mnew = fmaxf(mO[b], tmax);
        float corr = __expf(mO[b] - mnew);
        mO[b] = mnew;
        lp[b] *= corr;
#pragma unroll
        for (int d = 0; d < 4; d++)
#pragma unroll
          for (int r = 0; r < 4; r++) acc[d][b][r] *= corr;
        // P = exp(S - mnew) <= 1, pack to bf16 (RNE), store to per-warp LDS [q][kv]
        int rowo = (16 * b + l15) * 80;
#pragma unroll
        for (int a = 0; a < 2; a++) {
          float p0 = __expf(sacc[a][b][0] - mnew);
          float p1 = __expf(sacc[a][b][1] - mnew);
          float p2 = __expf(sacc[a][b][2] - mnew);
          float p3 = __expf(sacc[a][b][3] - mnew);
          lp[b] += (p0 + p1) + (p2 + p3);
          u32x2 w;
          w[0] = (unsigned)f2bf(p0) | ((unsigned)f2bf(p1) << 16);
          w[1] = (unsigned)f2bf(p2) | ((unsigned)f2bf(p3) << 16);
          *(u32x2*)(Pw + rowo + a * 32 + lhi * 8) = w;  // kv = 16a+4lhi+{0..3}
        }
      }
      // V^T A-frags: row=dd=16d+l15, k=kv=lhi*8+j
      short8 vfrag[4];
#pragma unroll
      for (int d = 0; d < 4; d++)
        vfrag[d] = *(const short8*)(vb + lhi * 1024 + (16 * d + l15) * 16);
      // P^T B-frags from LDS, then PV
#pragma unroll
      for (int b = 0; b < 2; b++) {
        short8 pbf = *(const short8*)(Pw + (16 * b + l15) * 80 + lhi * 16);
#pragma unroll
        for (int d = 0; d < 4; d++)
          acc[d][b] = __builtin_amdgcn_mfma_f32_16x16x32_bf16(vfrag[d], pbf, acc[d][b], 0, 0, 0);
      }
    }
  }

  const int bq = bh >> 5, h = bh & 31;
#pragma unroll
  for (int b = 0; b < 2; b++) {
    float l = lp[b];
    l += __shfl_xor(l, 16);
    l += __shfl_xor(l, 32);
    float inv = 1.f / l;
    int q = s5q * 32 + 16 * b + l15;
    unsigned short* row = ctx + ((size_t)(bq * 2048 + q)) * 2048 + h * 64;
#pragma unroll
    for (int d = 0; d < 4; d++) {
      int col = 16 * d + 4 * lhi;  // dd = col + reg
      u32x2 w;
      w[0] = (unsigned)f2bf(acc[d][b][0] * inv) | ((unsigned)f2bf(acc[d][b][1] * inv) << 16);
      w[1] = (unsigned)f2bf(acc[d][b][2] * inv) | ((unsigned)f2bf(acc[d][b][3] * inv) << 16);
      *(u32x2*)(row + col) = w;
    }
  }
}

// ---------------- launch ----------------
extern "C" void kernel_launch(void* const* d_in, const int* in_sizes, int n_in,
                              void* d_out, int out_size, void* d_ws, size_t ws_size,
                              hipStream_t stream) {
  const float* X  = (const float*)d_in[0];
  const float* Wq = (const float*)d_in[1];
  const float* bq = (const float*)d_in[2];
  const float* Wk = (const float*)d_in[3];
  const float* bk = (const float*)d_in[4];
  const float* Wv = (const float*)d_in[5];
  const float* bv = (const float*)d_in[6];
  const float* Wo = (const float*)d_in[7];
  const float* bo = (const float*)d_in[8];
  float* out = (float*)d_out;
  char* ws = (char*)d_ws;

  unsigned short* Xb  = (unsigned short*)(ws);                  // 16MB  [4096,2048] bf16
  unsigned short* Wtq = (unsigned short*)(ws + (16u << 20));    // 8MB   [N,K] bf16
  unsigned short* Wtk = (unsigned short*)(ws + (24u << 20));
  unsigned short* Wtv = (unsigned short*)(ws + (32u << 20));
  unsigned short* Wto = (unsigned short*)(ws + (40u << 20));
  unsigned short* Qf  = (unsigned short*)(ws + (48u << 20));    // 16MB frag layout
  unsigned short* Kf  = (unsigned short*)(ws + (64u << 20));    // 16MB frag layout
  unsigned short* Vf  = (unsigned short*)(ws + (80u << 20));    // 16MB frag layout
  unsigned short* Cb  = (unsigned short*)(ws + (96u << 20));    // 16MB [B,S,2048]

  cvt_x_k<<<dim3(1024), dim3(256), 0, stream>>>(X, Xb, (MROWS * HID) / 4);
  cvt_w_k<<<dim3(64, 64, 4), dim3(32, 8), 0, stream>>>(Wq, Wk, Wv, Wo, Wtq, Wtk, Wtv, Wto);
  qkv_gemm_k<<<dim3(16, 32, 3), dim3(256), 0, stream>>>(Xb, Wtq, Wtk, Wtv, bq, bk, bv, Qf, Kf, Vf);
  attn_k<<<dim3(16, 64), dim3(256), 0, stream>>>(Qf, Kf, Vf, Cb);
  gemm_k<<<dim3(16, 32), dim3(256), 0, stream>>>(Cb, Wto, bo, out);
}

// Round 6
// 439.056 us; speedup vs baseline: 1.4512x; 1.0301x over previous
//
#include <hip/hip_runtime.h>
#include <hip/hip_bf16.h>

#define HID 2048
#define SEQN 2048
#define NH 32
#define HD 64
#define NB 2
#define MROWS (NB * SEQN)  // 4096

using short8 = __attribute__((ext_vector_type(8))) short;
using f32x4  = __attribute__((ext_vector_type(4))) float;
using u32x2  = __attribute__((ext_vector_type(2))) unsigned;

__device__ __forceinline__ unsigned short f2bf(float f) {
  unsigned u = __float_as_uint(f);
  u += 0x7FFFu + ((u >> 16) & 1u);   // RNE
  return (unsigned short)(u >> 16);
}

__device__ __forceinline__ void gload16(const void* g, void* l) {
  __builtin_amdgcn_global_load_lds(
      (const __attribute__((address_space(1))) void*)g,
      (__attribute__((address_space(3))) void*)l, 16, 0, 0);
}

// ---------------- converters ----------------
__global__ void cvt_x_k(const float* __restrict__ x, unsigned short* __restrict__ o, int n4) {
  int i = blockIdx.x * blockDim.x + threadIdx.x;
  int stride = gridDim.x * blockDim.x;
  for (; i < n4; i += stride) {
    float4 v = ((const float4*)x)[i];
    ushort4 r;
    r.x = f2bf(v.x); r.y = f2bf(v.y); r.z = f2bf(v.z); r.w = f2bf(v.w);
    ((ushort4*)o)[i] = r;
  }
}

// Wt[n][k] = W[k][n], fp32 -> bf16
__global__ void cvt_w_k(const float* W0, const float* W1, const float* W2, const float* W3,
                        unsigned short* o0, unsigned short* o1, unsigned short* o2, unsigned short* o3) {
  const float* W = blockIdx.z == 0 ? W0 : blockIdx.z == 1 ? W1 : blockIdx.z == 2 ? W2 : W3;
  unsigned short* o = blockIdx.z == 0 ? o0 : blockIdx.z == 1 ? o1 : blockIdx.z == 2 ? o2 : o3;
  __shared__ float t[32][33];
  int n0 = blockIdx.x * 32, k0 = blockIdx.y * 32;
  int x = threadIdx.x, y = threadIdx.y;
#pragma unroll
  for (int i = 0; i < 4; i++)
    t[y + 8 * i][x] = W[(size_t)(k0 + y + 8 * i) * HID + n0 + x];
  __syncthreads();
#pragma unroll
  for (int i = 0; i < 4; i++)
    o[(size_t)(n0 + y + 8 * i) * HID + k0 + x] = f2bf(t[x][y + 8 * i]);
}

// ---------------- QKV GEMM: frag-native epilogues ----------------
// z=0 -> Qf (scaled by 0.125 = 1/sqrt(64)), z=1 -> Kf, z=2 -> Vf
// Qf/Kf layout: [bh][s5][dg=dd>>3][r=s&31][j=dd&7]   (elem idx)
// Vf   layout: [bh][s5][kg=(s>>3)&3][d=dd][j=s&7]
__global__ __launch_bounds__(256) void qkv_gemm_k(const unsigned short* __restrict__ A,
                                                  const unsigned short* __restrict__ W0,
                                                  const unsigned short* __restrict__ W1,
                                                  const unsigned short* __restrict__ W2,
                                                  const float* __restrict__ b0,
                                                  const float* __restrict__ b1,
                                                  const float* __restrict__ b2,
                                                  unsigned short* __restrict__ o0,
                                                  unsigned short* __restrict__ o1,
                                                  unsigned short* __restrict__ o2) {
  const int z = blockIdx.z;
  const unsigned short* Bt = z == 0 ? W0 : z == 1 ? W1 : W2;
  const float* bias = z == 0 ? b0 : z == 1 ? b1 : b2;
  unsigned short* out = z == 0 ? o0 : z == 1 ? o1 : o2;
  const float scale = z == 0 ? 0.125f : 1.0f;

  __shared__ __align__(16) unsigned short As[128 * 64];
  __shared__ __align__(16) unsigned short Bs[128 * 64];
  const int tid = threadIdx.x;
  const int wid = tid >> 6, lane = tid & 63;
  const int l15 = lane & 15, lhi = lane >> 4;
  const int wr = wid >> 1, wc = wid & 1;
  const int tileM = blockIdx.y * 128, tileN = blockIdx.x * 128;
  f32x4 acc[4][4] = {};

  for (int k0 = 0; k0 < HID; k0 += 64) {
#pragma unroll
    for (int i = 0; i < 4; i++) {
      int X = (i * 256 + tid) * 16;
      int r = X >> 7, y = X & 127;
      int srcb = y ^ ((r & 7) << 4);
      const char* ga = (const char*)A + ((size_t)(tileM + r) * HID + k0) * 2 + srcb;
      const char* gb = (const char*)Bt + ((size_t)(tileN + r) * HID + k0) * 2 + srcb;
      gload16(ga, (char*)As + i * 4096 + wid * 1024);
      gload16(gb, (char*)Bs + i * 4096 + wid * 1024);
    }
    __syncthreads();
#pragma unroll
    for (int ks = 0; ks < 2; ks++) {
      short8 af[4], bfr[4];
      int off = ks * 64 + lhi * 16;
#pragma unroll
      for (int mf = 0; mf < 4; mf++) {
        int r = wr * 64 + mf * 16 + l15;
        af[mf] = *(const short8*)((const char*)As + r * 128 + (off ^ ((r & 7) << 4)));
      }
#pragma unroll
      for (int nf = 0; nf < 4; nf++) {
        int r = wc * 64 + nf * 16 + l15;
        bfr[nf] = *(const short8*)((const char*)Bs + r * 128 + (off ^ ((r & 7) << 4)));
      }
#pragma unroll
      for (int mf = 0; mf < 4; mf++)
#pragma unroll
        for (int nf = 0; nf < 4; nf++)
          acc[mf][nf] = __builtin_amdgcn_mfma_f32_16x16x32_bf16(af[mf], bfr[nf], acc[mf][nf], 0, 0, 0);
    }
    __syncthreads();
  }

#pragma unroll
  for (int mf = 0; mf < 4; mf++) {
#pragma unroll
    for (int nf = 0; nf < 4; nf++) {
      int n = tileN + wc * 64 + nf * 16 + l15;
      float bv = bias[n];
      int h = n >> 6, dd = n & 63;
#pragma unroll
      for (int reg = 0; reg < 4; reg++) {
        int m = tileM + wr * 64 + mf * 16 + lhi * 4 + reg;
        float v = (acc[mf][nf][reg] + bv) * scale;
        int b = m >> 11, s = m & 2047;
        size_t base = (size_t)((b << 5) + h) * 131072 + (size_t)(s >> 5) * 2048;
        size_t idx = (z < 2) ? base + (size_t)((dd >> 3) * 256 + (s & 31) * 8 + (dd & 7))
                             : base + (size_t)(((s >> 3) & 3) * 512 + dd * 8 + (s & 7));
        out[idx] = f2bf(v);
      }
    }
  }
}

// ---------------- GEMM (final projection): C = A @ Wt^T + bias, f32 out ----------------
__global__ __launch_bounds__(256) void gemm_k(const unsigned short* __restrict__ A,
                                              const unsigned short* __restrict__ Bt,
                                              const float* __restrict__ bias,
                                              float* __restrict__ out) {
  __shared__ __align__(16) unsigned short As[128 * 64];
  __shared__ __align__(16) unsigned short Bs[128 * 64];
  const int tid = threadIdx.x;
  const int wid = tid >> 6, lane = tid & 63;
  const int l15 = lane & 15, lhi = lane >> 4;
  const int wr = wid >> 1, wc = wid & 1;
  const int tileM = blockIdx.y * 128, tileN = blockIdx.x * 128;
  f32x4 acc[4][4] = {};

  for (int k0 = 0; k0 < HID; k0 += 64) {
#pragma unroll
    for (int i = 0; i < 4; i++) {
      int X = (i * 256 + tid) * 16;
      int r = X >> 7, y = X & 127;
      int srcb = y ^ ((r & 7) << 4);
      const char* ga = (const char*)A + ((size_t)(tileM + r) * HID + k0) * 2 + srcb;
      const char* gb = (const char*)Bt + ((size_t)(tileN + r) * HID + k0) * 2 + srcb;
      gload16(ga, (char*)As + i * 4096 + wid * 1024);
      gload16(gb, (char*)Bs + i * 4096 + wid * 1024);
    }
    __syncthreads();
#pragma unroll
    for (int ks = 0; ks < 2; ks++) {
      short8 af[4], bfr[4];
      int off = ks * 64 + lhi * 16;
#pragma unroll
      for (int mf = 0; mf < 4; mf++) {
        int r = wr * 64 + mf * 16 + l15;
        af[mf] = *(const short8*)((const char*)As + r * 128 + (off ^ ((r & 7) << 4)));
      }
#pragma unroll
      for (int nf = 0; nf < 4; nf++) {
        int r = wc * 64 + nf * 16 + l15;
        bfr[nf] = *(const short8*)((const char*)Bs + r * 128 + (off ^ ((r & 7) << 4)));
      }
#pragma unroll
      for (int mf = 0; mf < 4; mf++)
#pragma unroll
        for (int nf = 0; nf < 4; nf++)
          acc[mf][nf] = __builtin_amdgcn_mfma_f32_16x16x32_bf16(af[mf], bfr[nf], acc[mf][nf], 0, 0, 0);
    }
    __syncthreads();
  }

#pragma unroll
  for (int mf = 0; mf < 4; mf++) {
#pragma unroll
    for (int nf = 0; nf < 4; nf++) {
      int n = tileN + wc * 64 + nf * 16 + l15;
      float bv = bias[n];
#pragma unroll
      for (int reg = 0; reg < 4; reg++) {
        int m = tileM + wr * 64 + mf * 16 + lhi * 4 + reg;
        out[(size_t)m * HID + n] = acc[mf][nf][reg] + bv;
      }
    }
  }
}

// ---------------- flash attention: 16x16x32 MFMAs, round-5 numerics, b-split ----------------
// S^T tiles (a,b): kv=16a+lhi*4+reg, q=16b+l15 ; P via per-warp LDS (one b slice at a time).
// O^T tiles (d,b): dd=16d+lhi*4+reg, q=16b+l15 -> per-lane q -> scalar rescale.
// Qf/Kf: [bh][s5][dg][r][8] bf16 ; Vf: [bh][s5][kg][d][8] bf16 ; ctx: [B,S,2048] bf16
__global__ __launch_bounds__(256, 4) void attn_k(const unsigned short* __restrict__ Qf,
                                                 const unsigned short* __restrict__ Kf,
                                                 const unsigned short* __restrict__ Vf,
                                                 unsigned short* __restrict__ ctx) {
  __shared__ __align__(16) unsigned short Ks[2][4096];  // 8KB/buf: kv64 tile (2 s5 blocks)
  __shared__ __align__(16) unsigned short Vs[2][4096];
  __shared__ __align__(16) unsigned short Pb[4][640];   // per-warp P: [q16][kv32], stride 40sh=80B
  const int tid = threadIdx.x;
  const int lane = tid & 63, wid = tid >> 6;
  const int l15 = lane & 15, lhi = lane >> 4;
  // XCD swizzle: all 16 q-blocks of one bh land on one XCD (did%8 const)
  const int did = blockIdx.x + (blockIdx.y << 4);
  const int swz = (did & 7) * 128 + (did >> 3);
  const int bh = swz >> 4;
  const int s5q = (swz & 15) * 4 + wid;  // this warp's q 32-block
  const size_t hb = (size_t)bh * 131072;

  // Q B-frags (col=q=16b+l15, k=dd=32m+lhi*8+j), register-resident
  short8 qf[2][2];
#pragma unroll
  for (int m = 0; m < 2; m++)
#pragma unroll
    for (int b = 0; b < 2; b++)
      qf[m][b] = *(const short8*)(Qf + hb + (size_t)s5q * 2048 + (4 * m + lhi) * 256 + (16 * b + l15) * 8);

  f32x4 acc[4][2] = {};
  float mO[2] = {-1e30f, -1e30f}, lp[2] = {0.f, 0.f};

  const char* kg = (const char*)(Kf + hb);
  const char* vg = (const char*)(Vf + hb);
  char* Pw = (char*)&Pb[wid][0];

  // prologue: stage tile 0 into buf 0 (LDS dest wave-uniform; HW adds lane*16)
  gload16(kg + tid * 16, (char*)&Ks[0][0] + wid * 1024);
  gload16(kg + 4096 + tid * 16, (char*)&Ks[0][0] + 4096 + wid * 1024);
  gload16(vg + tid * 16, (char*)&Vs[0][0] + wid * 1024);
  gload16(vg + 4096 + tid * 16, (char*)&Vs[0][0] + 4096 + wid * 1024);

  for (int t = 0; t < 32; ++t) {
    __syncthreads();  // drains vmcnt/lgkmcnt; tile t staged, buf c^1 reads done
    const int c = t & 1;
    if (t + 1 < 32) {  // prefetch next tile into other buffer
      const char* kn = kg + (size_t)(t + 1) * 8192;
      const char* vn = vg + (size_t)(t + 1) * 8192;
      char* kl = (char*)&Ks[c ^ 1][0];
      char* vl = (char*)&Vs[c ^ 1][0];
      gload16(kn + tid * 16, kl + wid * 1024);
      gload16(kn + 4096 + tid * 16, kl + 4096 + wid * 1024);
      gload16(vn + tid * 16, vl + wid * 1024);
      gload16(vn + 4096 + tid * 16, vl + 4096 + wid * 1024);
    }
#pragma unroll
    for (int ks = 0; ks < 2; ++ks) {  // two kv32 sub-blocks
      const char* kb = (const char*)&Ks[c][0] + ks * 4096;
      const char* vb = (const char*)&Vs[c][0] + ks * 4096;
      // K A-frags: row=kv=16a+l15, k=dd=32m+lhi*8+j
      short8 kf[2][2];
#pragma unroll
      for (int a = 0; a < 2; a++)
#pragma unroll
        for (int m = 0; m < 2; m++)
          kf[a][m] = *(const short8*)(kb + (4 * m + lhi) * 512 + (16 * a + l15) * 16);
      // V^T A-frags: row=dd=16d+l15, k=kv=lhi*8+j   (hoisted: overlaps softmax VALU)
      short8 vfrag[4];
#pragma unroll
      for (int d = 0; d < 4; d++)
        vfrag[d] = *(const short8*)(vb + lhi * 1024 + (16 * d + l15) * 16);
      // S^T tiles
      f32x4 sacc[2][2] = {};
#pragma unroll
      for (int a = 0; a < 2; a++)
#pragma unroll
        for (int b = 0; b < 2; b++)
#pragma unroll
          for (int m = 0; m < 2; m++)
            sacc[a][b] = __builtin_amdgcn_mfma_f32_16x16x32_bf16(kf[a][m], qf[m][b], sacc[a][b], 0, 0, 0);
      // per-b: online softmax (round-5 numerics) + P-store + PV, one b slice at a time
#pragma unroll
      for (int b = 0; b < 2; b++) {
        float tmax = sacc[0][b][0];
#pragma unroll
        for (int a = 0; a < 2; a++)
#pragma unroll
          for (int r = 0; r < 4; r++) tmax = fmaxf(tmax, sacc[a][b][r]);
        tmax = fmaxf(tmax, __shfl_xor(tmax, 16));
        tmax = fmaxf(tmax, __shfl_xor(tmax, 32));
        float mnew = fmaxf(mO[b], tmax);
        // rescale-skip: when no lane's max grew, corr==exp(0)==1 exactly -> skipping is bit-identical
        if (__any(mnew > mO[b])) {
          float corr = __expf(mO[b] - mnew);
          lp[b] *= corr;
#pragma unroll
          for (int d = 0; d < 4; d++)
#pragma unroll
            for (int r = 0; r < 4; r++) acc[d][b][r] *= corr;
          mO[b] = mnew;
        }
        // P = exp(S - mO) <= 1, pack to bf16 (RNE), store to per-warp LDS [q16][kv32]
        int rowo = l15 * 80;
#pragma unroll
        for (int a = 0; a < 2; a++) {
          float p0 = __expf(sacc[a][b][0] - mO[b]);
          float p1 = __expf(sacc[a][b][1] - mO[b]);
          float p2 = __expf(sacc[a][b][2] - mO[b]);
          float p3 = __expf(sacc[a][b][3] - mO[b]);
          lp[b] += (p0 + p1) + (p2 + p3);
          u32x2 w;
          w[0] = (unsigned)f2bf(p0) | ((unsigned)f2bf(p1) << 16);
          w[1] = (unsigned)f2bf(p2) | ((unsigned)f2bf(p3) << 16);
          *(u32x2*)(Pw + rowo + a * 32 + lhi * 8) = w;  // kv = 16a+4lhi+{0..3}
        }
        // P^T B-frag from LDS, then PV
        short8 pbf = *(const short8*)(Pw + l15 * 80 + lhi * 16);
#pragma unroll
        for (int d = 0; d < 4; d++)
          acc[d][b] = __builtin_amdgcn_mfma_f32_16x16x32_bf16(vfrag[d], pbf, acc[d][b], 0, 0, 0);
      }
    }
  }

  const int bq = bh >> 5, h = bh & 31;
#pragma unroll
  for (int b = 0; b < 2; b++) {
    float l = lp[b];
    l += __shfl_xor(l, 16);
    l += __shfl_xor(l, 32);
    float inv = 1.f / l;
    int q = s5q * 32 + 16 * b + l15;
    unsigned short* row = ctx + ((size_t)(bq * 2048 + q)) * 2048 + h * 64;
#pragma unroll
    for (int d = 0; d < 4; d++) {
      int col = 16 * d + 4 * lhi;  // dd = col + reg
      u32x2 w;
      w[0] = (unsigned)f2bf(acc[d][b][0] * inv) | ((unsigned)f2bf(acc[d][b][1] * inv) << 16);
      w[1] = (unsigned)f2bf(acc[d][b][2] * inv) | ((unsigned)f2bf(acc[d][b][3] * inv) << 16);
      *(u32x2*)(row + col) = w;
    }
  }
}

// ---------------- launch ----------------
extern "C" void kernel_launch(void* const* d_in, const int* in_sizes, int n_in,
                              void* d_out, int out_size, void* d_ws, size_t ws_size,
                              hipStream_t stream) {
  const float* X  = (const float*)d_in[0];
  const float* Wq = (const float*)d_in[1];
  const float* bq = (const float*)d_in[2];
  const float* Wk = (const float*)d_in[3];
  const float* bk = (const float*)d_in[4];
  const float* Wv = (const float*)d_in[5];
  const float* bv = (const float*)d_in[6];
  const float* Wo = (const float*)d_in[7];
  const float* bo = (const float*)d_in[8];
  float* out = (float*)d_out;
  char* ws = (char*)d_ws;

  unsigned short* Xb  = (unsigned short*)(ws);                  // 16MB  [4096,2048] bf16
  unsigned short* Wtq = (unsigned short*)(ws + (16u << 20));    // 8MB   [N,K] bf16
  unsigned short* Wtk = (unsigned short*)(ws + (24u << 20));
  unsigned short* Wtv = (unsigned short*)(ws + (32u << 20));
  unsigned short* Wto = (unsigned short*)(ws + (40u << 20));
  unsigned short* Qf  = (unsigned short*)(ws + (48u << 20));    // 16MB frag layout
  unsigned short* Kf  = (unsigned short*)(ws + (64u << 20));    // 16MB frag layout
  unsigned short* Vf  = (unsigned short*)(ws + (80u << 20));    // 16MB frag layout
  unsigned short* Cb  = (unsigned short*)(ws + (96u << 20));    // 16MB [B,S,2048]

  cvt_x_k<<<dim3(1024), dim3(256), 0, stream>>>(X, Xb, (MROWS * HID) / 4);
  cvt_w_k<<<dim3(64, 64, 4), dim3(32, 8), 0, stream>>>(Wq, Wk, Wv, Wo, Wtq, Wtk, Wtv, Wto);
  qkv_gemm_k<<<dim3(16, 32, 3), dim3(256), 0, stream>>>(Xb, Wtq, Wtk, Wtv, bq, bk, bv, Qf, Kf, Vf);
  attn_k<<<dim3(16, 64), dim3(256), 0, stream>>>(Qf, Kf, Vf, Cb);
  gemm_k<<<dim3(16, 32), dim3(256), 0, stream>>>(Cb, Wto, bo, out);
}